// Round 4
// baseline (1764.589 us; speedup 1.0000x reference)
//
#include <hip/hip_runtime.h>
#include <cmath>

// ---------------- problem constants ----------------
// B=8, M=1024, D=768, N=32, P=32, K=8, H=2048
#define NB    8
#define MTOK  1024
#define BMT   8192      // B*M
#define DD    768
#define NEXP  32
#define PSLOT 32
#define NP    1024      // N*P
#define KTOP  8
#define HH    2048

#define LDS_S 40        // shorts per LDS row (80B, 16B-aligned); slots XOR-swizzled

typedef unsigned short ushort;
typedef __attribute__((ext_vector_type(8))) short short8v;   // 8 bf16 = 4 VGPR
typedef __attribute__((ext_vector_type(4))) short short4v;   // 8 bytes
typedef __attribute__((ext_vector_type(2))) short short2v;   // 4 bytes
typedef __attribute__((ext_vector_type(4))) float f32x4;

// f32 -> bf16 round-to-nearest-even
__device__ __forceinline__ ushort bf16_rne(float x) {
    unsigned u = __float_as_uint(x);
    unsigned r = (u + 0x7FFFu + ((u >> 16) & 1u)) >> 16;
    return (ushort)r;
}
__device__ __forceinline__ float bf16_to_f(ushort h) {
    return __uint_as_float(((unsigned)h) << 16);
}
__device__ __forceinline__ void split2(float x, ushort& hi, ushort& lo) {
    hi = bf16_rne(x);
    lo = bf16_rne(x - bf16_to_f(hi));
}

// ---------------- K1: token L2 normalize ----------------
__global__ __launch_bounds__(256) void norm_x(const float* __restrict__ x, float* __restrict__ xn) {
    int tok = blockIdx.x;
    int t = threadIdx.x;
    const float* p = x + (long)tok * DD;
    float v0 = p[t], v1 = p[t + 256], v2 = p[t + 512];
    float ss = v0 * v0 + v1 * v1 + v2 * v2;
#pragma unroll
    for (int o = 32; o; o >>= 1) ss += __shfl_xor(ss, o);
    __shared__ float sred[4];
    if ((t & 63) == 0) sred[t >> 6] = ss;
    __syncthreads();
    ss = sred[0] + sred[1] + sred[2] + sred[3];
    float inv = 1.0f / fmaxf(sqrtf(ss), 1e-12f);
    float* q = xn + (long)tok * DD;
    q[t] = v0 * inv; q[t + 256] = v1 * inv; q[t + 512] = v2 * inv;
}

// ---------------- K2: phi normalize (over D) + scale ----------------
__global__ __launch_bounds__(256) void norm_phi(const float* __restrict__ phi, const float* __restrict__ scale,
                                                float* __restrict__ phin) {
    int np = blockIdx.x * 256 + threadIdx.x;   // 0..1023
    float ss = 0.f;
    for (int d = 0; d < DD; ++d) {
        float v = phi[(long)d * NP + np];
        ss += v * v;
    }
    float sc = scale[0] / fmaxf(sqrtf(ss), 1e-12f);
    for (int d = 0; d < DD; ++d)
        phin[(long)d * NP + np] = phi[(long)d * NP + np] * sc;
}

// ---------------- K3: per-cluster sums (deterministic partials) ----------------
__global__ __launch_bounds__(256) void cluster_sum(const float* __restrict__ xn, const int* __restrict__ ca,
                                                   float* __restrict__ spart, float* __restrict__ cntpart) {
    __shared__ float s[NEXP][256];
    __shared__ float cnt[NEXP];
    int chunk = blockIdx.x, slice = blockIdx.y, t = threadIdx.x;
#pragma unroll
    for (int n = 0; n < NEXP; ++n) s[n][t] = 0.f;
    if (t < NEXP) cnt[t] = 0.f;
    __syncthreads();
    int tok0 = slice * 512;
    for (int i = 0; i < 512; ++i) {
        int tok = tok0 + i;
        int a = ca[tok * KTOP];
        float v = xn[(long)tok * DD + chunk * 256 + t];
        s[a][t] += v;
        if (chunk == 0 && t == 0) cnt[a] += 1.f;
    }
    __syncthreads();
    for (int n = 0; n < NEXP; ++n)
        spart[(long)slice * (NEXP * DD) + n * DD + chunk * 256 + t] = s[n][t];
    if (chunk == 0 && t < NEXP) cntpart[slice * NEXP + t] = cnt[t];
}

__global__ __launch_bounds__(256) void reduce_parts(const float* __restrict__ part, float* __restrict__ outv,
                                                    const float* __restrict__ cntpart, float* __restrict__ ccnt,
                                                    int doCnt) {
    int i = blockIdx.x * 256 + threadIdx.x;   // 0..24575
    float s = 0.f;
#pragma unroll
    for (int sl = 0; sl < 16; ++sl) s += part[(long)sl * (NEXP * DD) + i];
    outv[i] = s;
    if (doCnt && i < NEXP) {
        float c = 0.f;
#pragma unroll
        for (int sl = 0; sl < 16; ++sl) c += cntpart[sl * NEXP + i];
        ccnt[i] = c;
    }
}

// ---------------- K4: per-cluster MAD partials ----------------
__global__ __launch_bounds__(256) void cluster_mad(const float* __restrict__ xn, const int* __restrict__ ca,
                                                   const float* __restrict__ csum, const float* __restrict__ ccnt,
                                                   float* __restrict__ mpart) {
    __shared__ float md[NEXP][256];
    __shared__ float mean[NEXP][256];
    int chunk = blockIdx.x, slice = blockIdx.y, t = threadIdx.x;
#pragma unroll
    for (int n = 0; n < NEXP; ++n) {
        float c = ccnt[n];
        mean[n][t] = (c > 0.f) ? csum[n * DD + chunk * 256 + t] / c : 0.f;
        md[n][t] = 0.f;
    }
    __syncthreads();
    int tok0 = slice * 512;
    for (int i = 0; i < 512; ++i) {
        int tok = tok0 + i;
        int a = ca[tok * KTOP];
        float v = xn[(long)tok * DD + chunk * 256 + t];
        md[a][t] += fabsf(v - mean[a][t]);
    }
    __syncthreads();
    for (int n = 0; n < NEXP; ++n)
        mpart[(long)slice * (NEXP * DD) + n * DD + chunk * 256 + t] = md[n][t];
}

// ---------------- K5: W = normalize(clamp(1/(mad+0.35))) ----------------
__global__ __launch_bounds__(1024) void compute_W(const float* __restrict__ cmad, const float* __restrict__ ccnt,
                                                  float* __restrict__ W) {
    __shared__ float s[16];
    int t = threadIdx.x;
    auto block_sum = [&](float v) -> float {
#pragma unroll
        for (int o = 32; o; o >>= 1) v += __shfl_xor(v, o);
        if ((t & 63) == 0) s[t >> 6] = v;
        __syncthreads();
        float tot = 0.f;
#pragma unroll
        for (int i = 0; i < 16; ++i) tot += s[i];
        __syncthreads();
        return tot;
    };
    const int TOT = NEXP * DD;  // 24576
    float p = 0.f;
    for (int i = t; i < TOT; i += 1024) {
        int n = i / DD;
        float c = ccnt[n];
        float wm = (c > 0.f) ? cmad[i] / c : 0.f;
        p += 1.f / (wm + 0.35f);
    }
    float mean1 = block_sum(p) / (float)TOT;
    float clamp = 5.f * mean1;
    p = 0.f;
    for (int i = t; i < TOT; i += 1024) {
        int n = i / DD;
        float c = ccnt[n];
        float wm = (c > 0.f) ? cmad[i] / c : 0.f;
        p += fminf(1.f / (wm + 0.35f), clamp);
    }
    float mean2 = block_sum(p) / (float)TOT;
    float inv2 = 1.f / mean2;
    for (int i = t; i < TOT; i += 1024) {
        int n = i / DD;
        float c = ccnt[n];
        float wm = (c > 0.f) ? cmad[i] / c : 0.f;
        W[i] = fminf(1.f / (wm + 0.35f), clamp) * inv2;
    }
}

// ---------------- K6: xn *= W[assign] ----------------
__global__ __launch_bounds__(192) void apply_W(float* __restrict__ xn, const int* __restrict__ ca,
                                               const float* __restrict__ W) {
    int tok = blockIdx.x;
    int d4 = threadIdx.x * 4;
    int a = ca[tok * KTOP];
    float4 v = *reinterpret_cast<float4*>(xn + (long)tok * DD + d4);
    float4 w = *reinterpret_cast<const float4*>(W + a * DD + d4);
    v.x *= w.x; v.y *= w.y; v.z *= w.z; v.w *= w.w;
    *reinterpret_cast<float4*>(xn + (long)tok * DD + d4) = v;
}

// ---------------- MFMA split-bf16 GEMM: BM=256, BN=128, BK=32, 512 thr ----------------
// Register-prefetch pipelined: LOAD(t+1) issued before COMPUTE(t); split+LDS-write after.
// AMODE 0: A from pre-split bf16 pair, rows via expert remap.
// AMODE 1: A from f32, k-contiguous rows (+ optional per-row softmax scale).
// AMODE 2: A from f32 transposed ((r,k) at Af32[k*lda+r]) (+ optional per-row scale).
// EPI: 0 none, 1 +bias, 2 +bias+gelu.  WSPLIT: C -> bf16 pair.  CEMAP: expert remap C rows.
template <int AMODE, bool SCALE, int EPI, bool WSPLIT, bool CEMAP>
__global__ __launch_bounds__(512, 4) void gemm_mfma(
    const ushort* __restrict__ Ahi, const ushort* __restrict__ Alo,
    const float* __restrict__ Af32, const float* __restrict__ B,
    float* __restrict__ Cf, ushort* __restrict__ Chi, ushort* __restrict__ Clo,
    int N, int K, int lda, int ldb, int ldc,
    long sA, long sB, long sC,
    const float* __restrict__ smax, const float* __restrict__ sinv, int sScale,
    const float* __restrict__ bias, int biasStride) {
    __shared__ __attribute__((aligned(16))) ushort Ah[256 * LDS_S];
    __shared__ __attribute__((aligned(16))) ushort Al[256 * LDS_S];
    __shared__ __attribute__((aligned(16))) ushort Bh[128 * LDS_S];
    __shared__ __attribute__((aligned(16))) ushort Bl[128 * LDS_S];

    // XCD-aware bijective remap (all grids are multiples of 8)
    int orig = blockIdx.x + gridDim.x * (blockIdx.y + gridDim.y * blockIdx.z);
    int nwg = gridDim.x * gridDim.y * gridDim.z;
    int wg = (orig & 7) * (nwg >> 3) + (orig >> 3);
    int bx = wg % gridDim.x;
    int rest = wg / gridDim.x;
    int by = rest % gridDim.y;
    int z  = rest / gridDim.y;
    const int m0 = by * 256;
    const int n0 = bx * 128;

    const int tid = threadIdx.x;
    const int lane = tid & 63, w = tid >> 6;
    const int wr = w >> 1, wc = w & 1;            // 4x2 waves of 64x64
    const int lr = lane & 15, kh = lane >> 4;
    const int xorv = (lr >> 2) & 3;               // frag-row swizzle key

    // ---- fixed per-thread staging coordinates
    const int kqB  = (tid >> 3) & 7;                    // B: k quad
    const int nqB  = (tid & 7) | (((tid >> 6) & 3) << 3);
    const int dkh  = tid >> 8;                          // B: 0..1
    const int rq2  = (tid & 7) | ((tid >> 6) << 3);     // AMODE2 row quad
    const int kq2  = (tid >> 3) & 7;                    // AMODE2 k quad

    f32x4 acc[4][4];
#pragma unroll
    for (int i = 0; i < 4; ++i)
#pragma unroll
        for (int j = 0; j < 4; ++j) acc[i][j] = (f32x4)(0.f);

    const long zs = (long)z * sScale;

    // ---- hoisted per-row softmax scale (K-invariant)
    float hmx[4], hsi[4];
    if constexpr (SCALE && AMODE == 1) {
#pragma unroll
        for (int i = 0; i < 4; ++i) {
            int rg = m0 + ((tid + i * 512) >> 3);
            hmx[i] = smax[zs + rg]; hsi[i] = sinv[zs + rg];
        }
    }
    if constexpr (SCALE && AMODE == 2) {
        float4 mx4 = *reinterpret_cast<const float4*>(smax + zs + m0 + rq2 * 4);
        float4 si4 = *reinterpret_cast<const float4*>(sinv + zs + m0 + rq2 * 4);
        hmx[0] = mx4.x; hmx[1] = mx4.y; hmx[2] = mx4.z; hmx[3] = mx4.w;
        hsi[0] = si4.x; hsi[1] = si4.y; hsi[2] = si4.z; hsi[3] = si4.w;
    }

    // ---- register staging buffers
    short8v rAh[2], rAl[2];       // AMODE0
    float4  rA[4];                // AMODE1/2
    float4  rB[2];

    auto LOAD = [&](int kk0) {
        if constexpr (AMODE == 0) {
#pragma unroll
            for (int i = 0; i < 2; ++i) {
                int g = tid + i * 512;
                int r = g >> 2, kg = g & 3;
                int rg = m0 + r;
                long roff = ((long)(rg >> 5) * NP + (long)z * PSLOT + (rg & 31)) * lda;
                long o = roff + kk0 + kg * 8;
                rAh[i] = *reinterpret_cast<const short8v*>(Ahi + o);
                rAl[i] = *reinterpret_cast<const short8v*>(Alo + o);
            }
        } else if constexpr (AMODE == 1) {
#pragma unroll
            for (int i = 0; i < 4; ++i) {
                int g = tid + i * 512;
                int r = g >> 3, kq = g & 7;
                rA[i] = *reinterpret_cast<const float4*>(Af32 + (long)z * sA + (long)(m0 + r) * lda + kk0 + kq * 4);
            }
        } else {
#pragma unroll
            for (int dk = 0; dk < 4; ++dk)
                rA[dk] = *reinterpret_cast<const float4*>(
                    Af32 + (long)z * sA + (long)(kk0 + kq2 * 4 + dk) * lda + m0 + rq2 * 4);
        }
#pragma unroll
        for (int dd = 0; dd < 2; ++dd)
            rB[dd] = *reinterpret_cast<const float4*>(
                B + (long)z * sB + (long)(kk0 + kqB * 4 + dkh * 2 + dd) * ldb + n0 + nqB * 4);
    };

    auto WRITE = [&]() {
        // ---- A
        if constexpr (AMODE == 0) {
#pragma unroll
            for (int i = 0; i < 2; ++i) {
                int g = tid + i * 512;
                int r = g >> 2, kg = g & 3;
                int ls = r * LDS_S + ((kg ^ ((r >> 2) & 3)) << 3);
                *reinterpret_cast<short8v*>(&Ah[ls]) = rAh[i];
                *reinterpret_cast<short8v*>(&Al[ls]) = rAl[i];
            }
        } else if constexpr (AMODE == 1) {
#pragma unroll
            for (int i = 0; i < 4; ++i) {
                int g = tid + i * 512;
                int r = g >> 3, kq = g & 7;
                float f0, f1, f2, f3;
                if constexpr (SCALE) {
                    f0 = __expf(rA[i].x - hmx[i]) * hsi[i]; f1 = __expf(rA[i].y - hmx[i]) * hsi[i];
                    f2 = __expf(rA[i].z - hmx[i]) * hsi[i]; f3 = __expf(rA[i].w - hmx[i]) * hsi[i];
                } else { f0 = rA[i].x; f1 = rA[i].y; f2 = rA[i].z; f3 = rA[i].w; }
                ushort h0,h1,h2,h3,l0,l1,l2,l3;
                split2(f0,h0,l0); split2(f1,h1,l1); split2(f2,h2,l2); split2(f3,h3,l3);
                int ls = r * LDS_S + (((kq >> 1) ^ ((r >> 2) & 3)) << 3) + ((kq & 1) << 2);
                *reinterpret_cast<short4v*>(&Ah[ls]) = short4v{(short)h0,(short)h1,(short)h2,(short)h3};
                *reinterpret_cast<short4v*>(&Al[ls]) = short4v{(short)l0,(short)l1,(short)l2,(short)l3};
            }
        } else {
            float vals[4][4];   // [dk][dr]
#pragma unroll
            for (int dk = 0; dk < 4; ++dk) {
                vals[dk][0] = rA[dk].x; vals[dk][1] = rA[dk].y;
                vals[dk][2] = rA[dk].z; vals[dk][3] = rA[dk].w;
            }
            ushort h[4][4], l[4][4];
#pragma unroll
            for (int dk = 0; dk < 4; ++dk)
#pragma unroll
                for (int dr = 0; dr < 4; ++dr) {
                    float f = vals[dk][dr];
                    if constexpr (SCALE) f = __expf(f - hmx[dr]) * hsi[dr];
                    split2(f, h[dk][dr], l[dk][dr]);
                }
#pragma unroll
            for (int dr = 0; dr < 4; ++dr) {
                int r = rq2 * 4 + dr;
                int ls = r * LDS_S + (((kq2 >> 1) ^ ((r >> 2) & 3)) << 3) + ((kq2 & 1) << 2);
                *reinterpret_cast<short4v*>(&Ah[ls]) =
                    short4v{(short)h[0][dr], (short)h[1][dr], (short)h[2][dr], (short)h[3][dr]};
                *reinterpret_cast<short4v*>(&Al[ls]) =
                    short4v{(short)l[0][dr], (short)l[1][dr], (short)l[2][dr], (short)l[3][dr]};
            }
        }
        // ---- B
        {
            ushort h[2][4], l[2][4];
            float va[2][4];
            va[0][0] = rB[0].x; va[0][1] = rB[0].y; va[0][2] = rB[0].z; va[0][3] = rB[0].w;
            va[1][0] = rB[1].x; va[1][1] = rB[1].y; va[1][2] = rB[1].z; va[1][3] = rB[1].w;
#pragma unroll
            for (int dd = 0; dd < 2; ++dd)
#pragma unroll
                for (int dn = 0; dn < 4; ++dn) split2(va[dd][dn], h[dd][dn], l[dd][dn]);
#pragma unroll
            for (int dn = 0; dn < 4; ++dn) {
                int r = nqB * 4 + dn;
                int ls = r * LDS_S + (((kqB >> 1) ^ ((r >> 2) & 3)) << 3) + ((kqB & 1) << 2) + dkh * 2;
                *reinterpret_cast<short2v*>(&Bh[ls]) = short2v{(short)h[0][dn], (short)h[1][dn]};
                *reinterpret_cast<short2v*>(&Bl[ls]) = short2v{(short)l[0][dn], (short)l[1][dn]};
            }
        }
    };

    auto COMPUTE = [&]() {
        short8v b_h[4], b_l[4];
#pragma unroll
        for (int nj = 0; nj < 4; ++nj) {
            int row = wc * 64 + nj * 16 + lr;
            int ls = row * LDS_S + ((kh ^ xorv) << 3);
            b_h[nj] = *reinterpret_cast<const short8v*>(&Bh[ls]);
            b_l[nj] = *reinterpret_cast<const short8v*>(&Bl[ls]);
        }
#pragma unroll
        for (int mi = 0; mi < 4; ++mi) {
            int row = wr * 64 + mi * 16 + lr;
            int ls = row * LDS_S + ((kh ^ xorv) << 3);
            short8v ah = *reinterpret_cast<const short8v*>(&Ah[ls]);
            short8v al = *reinterpret_cast<const short8v*>(&Al[ls]);
#pragma unroll
            for (int nj = 0; nj < 4; ++nj) {
                acc[mi][nj] = __builtin_amdgcn_mfma_f32_16x16x32_bf16(ah, b_h[nj], acc[mi][nj], 0, 0, 0);
                acc[mi][nj] = __builtin_amdgcn_mfma_f32_16x16x32_bf16(ah, b_l[nj], acc[mi][nj], 0, 0, 0);
                acc[mi][nj] = __builtin_amdgcn_mfma_f32_16x16x32_bf16(al, b_h[nj], acc[mi][nj], 0, 0, 0);
            }
        }
    };

    // ---- pipelined K-loop: LOAD(t+1) || COMPUTE(t)
    const int nt = K >> 5;
    LOAD(0);
    WRITE();
    __syncthreads();
    for (int t = 0; t < nt; ++t) {
        if (t + 1 < nt) LOAD((t + 1) << 5);
        COMPUTE();
        __syncthreads();
        if (t + 1 < nt) {
            WRITE();
            __syncthreads();
        }
    }

    // ---------- epilogue ----------
#pragma unroll
    for (int mi = 0; mi < 4; ++mi)
#pragma unroll
        for (int j = 0; j < 4; ++j) {
            int rg = m0 + wr * 64 + mi * 16 + kh * 4 + j;
            long roff;
            if constexpr (CEMAP) roff = ((long)(rg >> 5) * NP + (long)z * PSLOT + (rg & 31)) * ldc;
            else                 roff = (long)z * sC + (long)rg * ldc;
#pragma unroll
            for (int nj = 0; nj < 4; ++nj) {
                int col = n0 + wc * 64 + nj * 16 + lr;
                float v = acc[mi][nj][j];
                if constexpr (EPI >= 1) v += bias[(long)z * biasStride + col];
                if constexpr (EPI == 2) v = 0.5f * v * (1.0f + erff(v * 0.70710678118654752f));
                if constexpr (WSPLIT) {
                    ushort h, l; split2(v, h, l);
                    Chi[roff + col] = h; Clo[roff + col] = l;
                } else {
                    Cf[roff + col] = v;
                }
            }
        }
}

// ---------------- K8: per-row top-8 + row softmax stats ----------------
__global__ __launch_bounds__(64) void row_topk(const float* __restrict__ logits,
                                               float* __restrict__ mix_out, float* __restrict__ clus_out,
                                               float* __restrict__ rowmax, float* __restrict__ rowsumInv) {
    int row = blockIdx.x;
    int lane = threadIdx.x;
    const float* p = logits + (long)row * NP;
    float v[16];
#pragma unroll
    for (int i = 0; i < 16; ++i) v[i] = p[lane + i * 64];
    float mx = v[0];
#pragma unroll
    for (int i = 1; i < 16; ++i) mx = fmaxf(mx, v[i]);
#pragma unroll
    for (int o = 32; o; o >>= 1) mx = fmaxf(mx, __shfl_xor(mx, o));
    float s = 0.f;
#pragma unroll
    for (int i = 0; i < 16; ++i) s += __expf(v[i] - mx);
#pragma unroll
    for (int o = 32; o; o >>= 1) s += __shfl_xor(s, o);
    if (lane == 0) { rowmax[row] = mx; rowsumInv[row] = 1.0f / s; }
#pragma unroll
    for (int k = 0; k < KTOP; ++k) {
        float bv = -INFINITY; int bi = 1 << 30;
#pragma unroll
        for (int i = 0; i < 16; ++i) {
            if (v[i] > bv) { bv = v[i]; bi = lane + i * 64; }
        }
#pragma unroll
        for (int o = 32; o; o >>= 1) {
            float ov = __shfl_xor(bv, o); int oi = __shfl_xor(bi, o);
            if (ov > bv || (ov == bv && oi < bi)) { bv = ov; bi = oi; }
        }
        int owner = bi & 63, slot = bi >> 6;
        if (lane == owner) {
#pragma unroll
            for (int i = 0; i < 16; ++i) if (slot == i) v[i] = -INFINITY;
        }
        if (lane == k) {
            mix_out[(long)row * KTOP + k] = bv;
            clus_out[(long)row * KTOP + k] = (float)(bi >> 5);
        }
    }
}

// ---------------- K9: column softmax stats ----------------
__global__ __launch_bounds__(256) void col_stats_part(const float* __restrict__ logits,
                                                      float* __restrict__ pmax, float* __restrict__ psum) {
    int b = blockIdx.z, ms = blockIdx.y, npc = blockIdx.x;
    int np = npc * 256 + threadIdx.x;
    const float* p = logits + ((long)b * MTOK + ms * 128) * NP + np;
    float mx = -INFINITY, s = 0.f;
    for (int m = 0; m < 128; ++m) {
        float v = p[(long)m * NP];
        float nm = fmaxf(mx, v);
        s = s * __expf(mx - nm) + __expf(v - nm);
        mx = nm;
    }
    long o = ((long)b * 8 + ms) * NP + np;
    pmax[o] = mx; psum[o] = s;
}

__global__ __launch_bounds__(256) void col_stats_merge(const float* __restrict__ pmax, const float* __restrict__ psum,
                                                       float* __restrict__ cmax, float* __restrict__ csumInv) {
    int b = blockIdx.y;
    int np = blockIdx.x * 256 + threadIdx.x;
    float mx = -INFINITY;
#pragma unroll
    for (int ms = 0; ms < 8; ++ms) mx = fmaxf(mx, pmax[((long)b * 8 + ms) * NP + np]);
    float s = 0.f;
#pragma unroll
    for (int ms = 0; ms < 8; ++ms) {
        long o = ((long)b * 8 + ms) * NP + np;
        s += psum[o] * __expf(pmax[o] - mx);
    }
    cmax[(long)b * NP + np] = mx;
    csumInv[(long)b * NP + np] = 1.0f / s;
}

// ---------------- launch ----------------
extern "C" void kernel_launch(void* const* d_in, const int* in_sizes, int n_in,
                              void* d_out, int out_size, void* d_ws, size_t ws_size,
                              hipStream_t stream) {
    const float* x    = (const float*)d_in[0];
    const int*   ca   = (const int*)d_in[1];
    const float* phi  = (const float*)d_in[2];
    const float* scale= (const float*)d_in[3];
    const float* w1   = (const float*)d_in[4];
    const float* b1   = (const float*)d_in[5];
    const float* w2   = (const float*)d_in[6];
    const float* b2   = (const float*)d_in[7];
    float* out = (float*)d_out;
    float* ws  = (float*)d_ws;

    float* xn        = ws;                    // 6291456 f32
    float* phin      = xn + 6291456;          // 786432
    float* logits    = phin + 786432;         // 8388608
    ushort* xs_hi    = (ushort*)(logits + 8388608);   // 6291456 shorts
    ushort* xs_lo    = xs_hi + 6291456;               // 6291456 shorts
    ushort* h_hi     = (ushort*)((float*)xs_hi + 6291456);  // 16777216 shorts
    ushort* h_lo     = h_hi + 16777216;
    float* after_h   = (float*)xs_hi + 6291456 + 16777216;
    float* rowmax    = after_h;               // 8192
    float* rowsumInv = rowmax + 8192;
    float* colmax    = rowsumInv + 8192;
    float* colsumInv = colmax + 8192;
    float* pmax      = colsumInv + 8192;      // 65536
    float* psum      = pmax + 65536;          // 65536
    float* csum      = psum + 65536;          // 24576
    float* cmad      = csum + 24576;          // 24576
    float* Wbuf      = cmad + 24576;          // 24576
    float* ccnt      = Wbuf + 24576;          // 64
    float* spart     = ccnt + 64;             // 393216
    float* mpart     = spart + 393216;        // 393216
    float* cntpart   = mpart + 393216;        // 512
    float* ys        = xn;                    // alias: xn dead after xs GEMM

    float* out_y    = out;
    float* out_mix  = out + 6291456;
    float* out_clus = out + 6291456 + 65536;

    norm_x<<<BMT, 256, 0, stream>>>(x, xn);
    norm_phi<<<4, 256, 0, stream>>>(phi, scale, phin);

    cluster_sum<<<dim3(3, 16), 256, 0, stream>>>(xn, ca, spart, cntpart);
    reduce_parts<<<96, 256, 0, stream>>>(spart, csum, cntpart, ccnt, 1);
    cluster_mad<<<dim3(3, 16), 256, 0, stream>>>(xn, ca, csum, ccnt, mpart);
    reduce_parts<<<96, 256, 0, stream>>>(mpart, cmad, nullptr, nullptr, 0);
    compute_W<<<1, 1024, 0, stream>>>(cmad, ccnt, Wbuf);
    apply_W<<<BMT, 192, 0, stream>>>(xn, ca, Wbuf);

    // logits = xn_w [8192x768] . phin [768x1024]  (split-bf16 MFMA, f32-accurate)
    gemm_mfma<1, false, 0, false, false><<<dim3(8, 32, 1), 512, 0, stream>>>(
        nullptr, nullptr, xn, phin, logits, nullptr, nullptr,
        NP, DD, DD, NP, NP, 0, 0, 0, nullptr, nullptr, 0, nullptr, 0);

    row_topk<<<BMT, 64, 0, stream>>>(logits, out_mix, out_clus, rowmax, rowsumInv);
    col_stats_part<<<dim3(4, 8, NB), 256, 0, stream>>>(logits, pmax, psum);
    col_stats_merge<<<dim3(4, NB), 256, 0, stream>>>(pmax, psum, colmax, colsumInv);

    // xs[b] = disp^T . xn[b] -> split bf16 pair
    gemm_mfma<2, true, 0, true, false><<<dim3(6, 4, NB), 512, 0, stream>>>(
        nullptr, nullptr, logits, xn, nullptr, xs_hi, xs_lo,
        DD, MTOK, NP, DD, DD,
        (long)MTOK * NP, (long)MTOK * DD, (long)NP * DD,
        colmax, colsumInv, NP, nullptr, 0);

    // h[n] = gelu(xs_rows(n) . w1[n] + b1[n]) -> split bf16 pair
    gemm_mfma<0, false, 2, true, true><<<dim3(16, 1, NEXP), 512, 0, stream>>>(
        xs_hi, xs_lo, nullptr, w1, nullptr, h_hi, h_lo,
        HH, DD, DD, HH, HH,
        0, (long)DD * HH, 0, nullptr, nullptr, 0, b1, HH);

    // ys[n] = h_rows(n) . w2[n] + b2[n] -> f32
    gemm_mfma<0, false, 1, false, true><<<dim3(6, 1, NEXP), 512, 0, stream>>>(
        h_hi, h_lo, nullptr, w2, ys, nullptr, nullptr,
        DD, HH, HH, DD, DD,
        0, (long)HH * DD, 0, nullptr, nullptr, 0, b2, DD);

    // y[b] = comb . ys[b] -> f32 out
    gemm_mfma<1, true, 0, false, false><<<dim3(6, 4, NB), 512, 0, stream>>>(
        nullptr, nullptr, logits, ys, out_y, nullptr, nullptr,
        DD, NP, NP, DD, DD,
        (long)MTOK * NP, (long)NP * DD, (long)MTOK * DD,
        rowmax, rowsumInv, MTOK, nullptr, 0);
}

// Round 5
// 761.485 us; speedup vs baseline: 2.3173x; 2.3173x over previous
//
#include <hip/hip_runtime.h>
#include <cmath>

// ---------------- problem constants ----------------
// B=8, M=1024, D=768, N=32, P=32, K=8, H=2048
#define NB    8
#define MTOK  1024
#define BMT   8192      // B*M
#define DD    768
#define NEXP  32
#define PSLOT 32
#define NP    1024      // N*P
#define KTOP  8
#define HH    2048

typedef unsigned short ushort;
typedef __attribute__((ext_vector_type(8))) short short8v;   // 8 bf16 = 4 VGPR
typedef __attribute__((ext_vector_type(4))) short short4v;   // 8 bytes
typedef __attribute__((ext_vector_type(4))) float f32x4;

__device__ __forceinline__ ushort bf16_rne(float x) {
    unsigned u = __float_as_uint(x);
    unsigned r = (u + 0x7FFFu + ((u >> 16) & 1u)) >> 16;
    return (ushort)r;
}
__device__ __forceinline__ float bf16_to_f(ushort h) {
    return __uint_as_float(((unsigned)h) << 16);
}
__device__ __forceinline__ void split2(float x, ushort& hi, ushort& lo) {
    hi = bf16_rne(x);
    lo = bf16_rne(x - bf16_to_f(hi));
}

// async global->LDS, 16B per lane; lds dest is wave-uniform base + lane*16
__device__ __forceinline__ void gl_lds16(const ushort* g, ushort* l) {
    __builtin_amdgcn_global_load_lds(
        (const __attribute__((address_space(1))) void*)g,
        (__attribute__((address_space(3))) void*)l, 16, 0, 0);
}

// ---------------- K1: token L2 normalize ----------------
__global__ __launch_bounds__(256) void norm_x(const float* __restrict__ x, float* __restrict__ xn) {
    int tok = blockIdx.x;
    int t = threadIdx.x;
    const float* p = x + (long)tok * DD;
    float v0 = p[t], v1 = p[t + 256], v2 = p[t + 512];
    float ss = v0 * v0 + v1 * v1 + v2 * v2;
#pragma unroll
    for (int o = 32; o; o >>= 1) ss += __shfl_xor(ss, o);
    __shared__ float sred[4];
    if ((t & 63) == 0) sred[t >> 6] = ss;
    __syncthreads();
    ss = sred[0] + sred[1] + sred[2] + sred[3];
    float inv = 1.0f / fmaxf(sqrtf(ss), 1e-12f);
    float* q = xn + (long)tok * DD;
    q[t] = v0 * inv; q[t + 256] = v1 * inv; q[t + 512] = v2 * inv;
}

// ---------------- K2: phi normalize -> transposed split pair [np][d] ----------------
__global__ __launch_bounds__(256) void norm_phi_T(const float* __restrict__ phi, const float* __restrict__ scale,
                                                  ushort* __restrict__ phT_hi, ushort* __restrict__ phT_lo) {
    int np = blockIdx.x;           // 1024 blocks
    int t = threadIdx.x;
    float ss = 0.f;
    for (int d = t; d < DD; d += 256) {
        float v = phi[(long)d * NP + np];
        ss += v * v;
    }
#pragma unroll
    for (int o = 32; o; o >>= 1) ss += __shfl_xor(ss, o);
    __shared__ float sred[4];
    if ((t & 63) == 0) sred[t >> 6] = ss;
    __syncthreads();
    ss = sred[0] + sred[1] + sred[2] + sred[3];
    float sc = scale[0] / fmaxf(sqrtf(ss), 1e-12f);
    for (int d = t; d < DD; d += 256) {
        float v = phi[(long)d * NP + np] * sc;
        ushort h, l; split2(v, h, l);
        phT_hi[(long)np * DD + d] = h;
        phT_lo[(long)np * DD + d] = l;
    }
}

// ---------------- K3: per-cluster sums (deterministic partials) ----------------
__global__ __launch_bounds__(256) void cluster_sum(const float* __restrict__ xn, const int* __restrict__ ca,
                                                   float* __restrict__ spart, float* __restrict__ cntpart) {
    __shared__ float s[NEXP][256];
    __shared__ float cnt[NEXP];
    int chunk = blockIdx.x, slice = blockIdx.y, t = threadIdx.x;
#pragma unroll
    for (int n = 0; n < NEXP; ++n) s[n][t] = 0.f;
    if (t < NEXP) cnt[t] = 0.f;
    __syncthreads();
    int tok0 = slice * 512;
    for (int i = 0; i < 512; ++i) {
        int tok = tok0 + i;
        int a = ca[tok * KTOP];
        float v = xn[(long)tok * DD + chunk * 256 + t];
        s[a][t] += v;
        if (chunk == 0 && t == 0) cnt[a] += 1.f;
    }
    __syncthreads();
    for (int n = 0; n < NEXP; ++n)
        spart[(long)slice * (NEXP * DD) + n * DD + chunk * 256 + t] = s[n][t];
    if (chunk == 0 && t < NEXP) cntpart[slice * NEXP + t] = cnt[t];
}

__global__ __launch_bounds__(256) void reduce_parts(const float* __restrict__ part, float* __restrict__ outv,
                                                    const float* __restrict__ cntpart, float* __restrict__ ccnt,
                                                    int doCnt) {
    int i = blockIdx.x * 256 + threadIdx.x;
    float s = 0.f;
#pragma unroll
    for (int sl = 0; sl < 16; ++sl) s += part[(long)sl * (NEXP * DD) + i];
    outv[i] = s;
    if (doCnt && i < NEXP) {
        float c = 0.f;
#pragma unroll
        for (int sl = 0; sl < 16; ++sl) c += cntpart[sl * NEXP + i];
        ccnt[i] = c;
    }
}

// ---------------- K4: per-cluster MAD partials ----------------
__global__ __launch_bounds__(256) void cluster_mad(const float* __restrict__ xn, const int* __restrict__ ca,
                                                   const float* __restrict__ csum, const float* __restrict__ ccnt,
                                                   float* __restrict__ mpart) {
    __shared__ float md[NEXP][256];
    __shared__ float mean[NEXP][256];
    int chunk = blockIdx.x, slice = blockIdx.y, t = threadIdx.x;
#pragma unroll
    for (int n = 0; n < NEXP; ++n) {
        float c = ccnt[n];
        mean[n][t] = (c > 0.f) ? csum[n * DD + chunk * 256 + t] / c : 0.f;
        md[n][t] = 0.f;
    }
    __syncthreads();
    int tok0 = slice * 512;
    for (int i = 0; i < 512; ++i) {
        int tok = tok0 + i;
        int a = ca[tok * KTOP];
        float v = xn[(long)tok * DD + chunk * 256 + t];
        md[a][t] += fabsf(v - mean[a][t]);
    }
    __syncthreads();
    for (int n = 0; n < NEXP; ++n)
        mpart[(long)slice * (NEXP * DD) + n * DD + chunk * 256 + t] = md[n][t];
}

// ---------------- K5: W = normalize(clamp(1/(mad+0.35))) ----------------
__global__ __launch_bounds__(1024) void compute_W(const float* __restrict__ cmad, const float* __restrict__ ccnt,
                                                  float* __restrict__ W) {
    __shared__ float s[16];
    int t = threadIdx.x;
    auto block_sum = [&](float v) -> float {
#pragma unroll
        for (int o = 32; o; o >>= 1) v += __shfl_xor(v, o);
        if ((t & 63) == 0) s[t >> 6] = v;
        __syncthreads();
        float tot = 0.f;
#pragma unroll
        for (int i = 0; i < 16; ++i) tot += s[i];
        __syncthreads();
        return tot;
    };
    const int TOT = NEXP * DD;
    float p = 0.f;
    for (int i = t; i < TOT; i += 1024) {
        int n = i / DD;
        float c = ccnt[n];
        float wm = (c > 0.f) ? cmad[i] / c : 0.f;
        p += 1.f / (wm + 0.35f);
    }
    float mean1 = block_sum(p) / (float)TOT;
    float clamp = 5.f * mean1;
    p = 0.f;
    for (int i = t; i < TOT; i += 1024) {
        int n = i / DD;
        float c = ccnt[n];
        float wm = (c > 0.f) ? cmad[i] / c : 0.f;
        p += fminf(1.f / (wm + 0.35f), clamp);
    }
    float mean2 = block_sum(p) / (float)TOT;
    float inv2 = 1.f / mean2;
    for (int i = t; i < TOT; i += 1024) {
        int n = i / DD;
        float c = ccnt[n];
        float wm = (c > 0.f) ? cmad[i] / c : 0.f;
        W[i] = fminf(1.f / (wm + 0.35f), clamp) * inv2;
    }
}

// ---------------- K6: xn *= W[assign] ----------------
__global__ __launch_bounds__(192) void apply_W(float* __restrict__ xn, const int* __restrict__ ca,
                                               const float* __restrict__ W) {
    int tok = blockIdx.x;
    int d4 = threadIdx.x * 4;
    int a = ca[tok * KTOP];
    float4 v = *reinterpret_cast<float4*>(xn + (long)tok * DD + d4);
    float4 w = *reinterpret_cast<const float4*>(W + a * DD + d4);
    v.x *= w.x; v.y *= w.y; v.z *= w.z; v.w *= w.w;
    *reinterpret_cast<float4*>(xn + (long)tok * DD + d4) = v;
}

// ---------------- K7: split xn -> bf16 hi/lo pair ----------------
__global__ __launch_bounds__(256) void split_xn(const float* __restrict__ xn,
                                                ushort* __restrict__ hi, ushort* __restrict__ lo) {
    long i4 = ((long)blockIdx.x * 256 + threadIdx.x) * 4;
    float4 v = *reinterpret_cast<const float4*>(xn + i4);
    ushort h0,h1,h2,h3,l0,l1,l2,l3;
    split2(v.x,h0,l0); split2(v.y,h1,l1); split2(v.z,h2,l2); split2(v.w,h3,l3);
    *reinterpret_cast<short4v*>(hi + i4) = short4v{(short)h0,(short)h1,(short)h2,(short)h3};
    *reinterpret_cast<short4v*>(lo + i4) = short4v{(short)l0,(short)l1,(short)l2,(short)l3};
}

// ---------------- MFMA GEMM: BM=128, BN=128, BK=32, 256 thr, dbuf 2-phase ----------------
// A (bf16, pre-rounded) staged via global_load_lds with pre-swizzled source.
// PAIR (logits): A and B are hi/lo pairs, both gload_lds, 3-MFMA split accumulate.
// !PAIR: B from f32 [k][n] source, reg-prefetch (16 floats) + micro-transpose + swizzled ds_write.
// Swizzle: 16B slot s of row r stored at s ^ ((r>>1)&3)  -> 2-way reads (free).
// AMAP: 0 linear z-strided, 1 token remap (row -> (r>>5)*1024 + z*32 + (r&31)).
// EPI: 0 none, 1 +bias, 2 +bias+gelu.  CBF16: round C to bf16.  CMAP: 0 lin, 1 token remap.
template <bool PAIR, int AMAP, int EPI, bool CBF16, int CMAP>
__global__ __launch_bounds__(256) void gemm2(
    const ushort* __restrict__ Ah_g, const ushort* __restrict__ Al_g,
    const float*  __restrict__ Bf_g,
    const ushort* __restrict__ Bh_g, const ushort* __restrict__ Bl_g,
    float* __restrict__ Cf, ushort* __restrict__ Cb,
    int K, int lda, int ldb, int ldc,
    long sA, long sB, long sC,
    const float* __restrict__ bias, int biasStride) {
    __shared__ __attribute__((aligned(16))) ushort lds[PAIR ? 32768 : 16384];

    // XCD-aware bijective remap (all grids multiples of 8)
    int orig = blockIdx.x + gridDim.x * (blockIdx.y + gridDim.y * blockIdx.z);
    int nwg = gridDim.x * gridDim.y * gridDim.z;
    int wg = (orig & 7) * (nwg >> 3) + (orig >> 3);
    int bx = wg % gridDim.x;
    int rest = wg / gridDim.x;
    int by = rest % gridDim.y;
    int z  = rest / gridDim.y;
    const int m0 = by * 128;
    const int n0 = bx * 128;

    const int tid = threadIdx.x, lane = tid & 63, w = tid >> 6;
    const int wr = w >> 1, wc = w & 1;          // 2x2 waves of 64x64
    const int lr = lane & 15, kh = lane >> 4;

    // staging coords: chunk c = i*256+tid; r=c>>2 row, sp=c&3 phys 16B slot
    long arow[2]; long brow[2]; int kOff[2];
#pragma unroll
    for (int i = 0; i < 2; ++i) {
        int c = i * 256 + tid;
        int r = c >> 2, sp = c & 3;
        kOff[i] = (sp ^ ((r >> 1) & 3)) << 3;   // element offset of logical slot
        int rg = m0 + r;
        if constexpr (AMAP == 0) arow[i] = (long)z * sA + (long)rg * lda;
        else arow[i] = ((long)(rg >> 5) * 1024 + (long)z * 32 + (rg & 31)) * (long)lda;
        brow[i] = (long)(n0 + r) * ldb;         // PAIR B rows (z=0 there)
    }
    // !PAIR B-staging coords
    const int kq = tid & 7, nq = tid >> 3;      // kq: 4 k-rows, nq: 4 n-cols
    float4 rB[4];

    f32x4 acc[4][4];
#pragma unroll
    for (int i = 0; i < 4; ++i)
#pragma unroll
        for (int j = 0; j < 4; ++j) acc[i][j] = (f32x4)(0.f);

    auto stage = [&](int buf, int kk0) {
#pragma unroll
        for (int i = 0; i < 2; ++i) {
            int ldso = (PAIR ? buf * 16384 : buf * 8192) + (i * 256 + w * 64) * 8;
            gl_lds16(Ah_g + arow[i] + kk0 + kOff[i], &lds[ldso]);
            if constexpr (PAIR)
                gl_lds16(Al_g + arow[i] + kk0 + kOff[i], &lds[ldso + 4096]);
        }
        if constexpr (PAIR) {
#pragma unroll
            for (int i = 0; i < 2; ++i) {
                int ldso = buf * 16384 + 8192 + (i * 256 + w * 64) * 8;
                gl_lds16(Bh_g + brow[i] + kk0 + kOff[i], &lds[ldso]);
                gl_lds16(Bl_g + brow[i] + kk0 + kOff[i], &lds[ldso + 4096]);
            }
        } else {
#pragma unroll
            for (int dk = 0; dk < 4; ++dk)
                rB[dk] = *reinterpret_cast<const float4*>(
                    Bf_g + (long)z * sB + (long)(kk0 + kq * 4 + dk) * ldb + n0 + nq * 4);
        }
    };

    auto bwrite = [&](int buf) {
        if constexpr (!PAIR) {
            ushort hv[4][4];
#pragma unroll
            for (int dk = 0; dk < 4; ++dk) {
                hv[dk][0] = bf16_rne(rB[dk].x); hv[dk][1] = bf16_rne(rB[dk].y);
                hv[dk][2] = bf16_rne(rB[dk].z); hv[dk][3] = bf16_rne(rB[dk].w);
            }
#pragma unroll
            for (int dn = 0; dn < 4; ++dn) {
                int n = nq * 4 + dn;
                int phys = (kq >> 1) ^ ((n >> 1) & 3);
                int off = buf * 8192 + 4096 + n * 32 + phys * 8 + (kq & 1) * 4;
                *reinterpret_cast<short4v*>(&lds[off]) =
                    short4v{(short)hv[0][dn], (short)hv[1][dn], (short)hv[2][dn], (short)hv[3][dn]};
            }
        }
    };

    auto compute = [&](int buf) {
        const int aB = PAIR ? buf * 16384 : buf * 8192;
        const int bB = PAIR ? buf * 16384 + 8192 : buf * 8192 + 4096;
        short8v bh[4], bl[4];
#pragma unroll
        for (int nj = 0; nj < 4; ++nj) {
            int rb = wc * 64 + nj * 16 + lr;
            int off = bB + rb * 32 + ((kh ^ ((rb >> 1) & 3)) << 3);
            bh[nj] = *reinterpret_cast<const short8v*>(&lds[off]);
            if constexpr (PAIR) bl[nj] = *reinterpret_cast<const short8v*>(&lds[off + 4096]);
        }
#pragma unroll
        for (int mi = 0; mi < 4; ++mi) {
            int ra = wr * 64 + mi * 16 + lr;
            int off = aB + ra * 32 + ((kh ^ ((ra >> 1) & 3)) << 3);
            short8v ah = *reinterpret_cast<const short8v*>(&lds[off]);
            if constexpr (PAIR) {
                short8v al = *reinterpret_cast<const short8v*>(&lds[off + 4096]);
#pragma unroll
                for (int nj = 0; nj < 4; ++nj) {
                    acc[mi][nj] = __builtin_amdgcn_mfma_f32_16x16x32_bf16(ah, bh[nj], acc[mi][nj], 0, 0, 0);
                    acc[mi][nj] = __builtin_amdgcn_mfma_f32_16x16x32_bf16(ah, bl[nj], acc[mi][nj], 0, 0, 0);
                    acc[mi][nj] = __builtin_amdgcn_mfma_f32_16x16x32_bf16(al, bh[nj], acc[mi][nj], 0, 0, 0);
                }
            } else {
#pragma unroll
                for (int nj = 0; nj < 4; ++nj)
                    acc[mi][nj] = __builtin_amdgcn_mfma_f32_16x16x32_bf16(ah, bh[nj], acc[mi][nj], 0, 0, 0);
            }
        }
    };

    // ---- 2-phase double-buffered K-loop
    const int nt = K >> 5;
    stage(0, 0);
    __syncthreads();                 // drains vmcnt -> A(0) in LDS, rB(0) in regs
    if constexpr (!PAIR) { bwrite(0); __syncthreads(); }
    for (int t = 0; t < nt; ++t) {
        int cur = t & 1;
        if (t + 1 < nt) stage(1 - cur, (t + 1) << 5);
        compute(cur);
        __syncthreads();             // drains vmcnt: next-tile A landed during compute
        if constexpr (!PAIR) {
            if (t + 1 < nt) { bwrite(1 - cur); __syncthreads(); }
        }
    }

    // ---- epilogue
#pragma unroll
    for (int mi = 0; mi < 4; ++mi)
#pragma unroll
        for (int j = 0; j < 4; ++j) {
            int rg = m0 + wr * 64 + mi * 16 + kh * 4 + j;
            long roff;
            if constexpr (CMAP == 1) roff = ((long)(rg >> 5) * 1024 + (long)z * 32 + (rg & 31)) * (long)ldc;
            else                     roff = (long)z * sC + (long)rg * ldc;
#pragma unroll
            for (int nj = 0; nj < 4; ++nj) {
                int col = n0 + wc * 64 + nj * 16 + lr;
                float v = acc[mi][nj][j];
                if constexpr (EPI >= 1) v += bias[(long)z * biasStride + col];
                if constexpr (EPI == 2) v = 0.5f * v * (1.0f + erff(v * 0.70710678118654752f));
                if constexpr (CBF16) Cb[roff + col] = bf16_rne(v);
                else                 Cf[roff + col] = v;
            }
        }
}

// ---------------- K8: per-row top-8 + row softmax stats ----------------
__global__ __launch_bounds__(64) void row_topk(const float* __restrict__ logits,
                                               float* __restrict__ mix_out, float* __restrict__ clus_out,
                                               float* __restrict__ rowmax, float* __restrict__ rowsumInv) {
    int row = blockIdx.x;
    int lane = threadIdx.x;
    const float* p = logits + (long)row * NP;
    float v[16];
#pragma unroll
    for (int i = 0; i < 16; ++i) v[i] = p[lane + i * 64];
    float mx = v[0];
#pragma unroll
    for (int i = 1; i < 16; ++i) mx = fmaxf(mx, v[i]);
#pragma unroll
    for (int o = 32; o; o >>= 1) mx = fmaxf(mx, __shfl_xor(mx, o));
    float s = 0.f;
#pragma unroll
    for (int i = 0; i < 16; ++i) s += __expf(v[i] - mx);
#pragma unroll
    for (int o = 32; o; o >>= 1) s += __shfl_xor(s, o);
    if (lane == 0) { rowmax[row] = mx; rowsumInv[row] = 1.0f / s; }
#pragma unroll
    for (int k = 0; k < KTOP; ++k) {
        float bv = -INFINITY; int bi = 1 << 30;
#pragma unroll
        for (int i = 0; i < 16; ++i) {
            if (v[i] > bv) { bv = v[i]; bi = lane + i * 64; }
        }
#pragma unroll
        for (int o = 32; o; o >>= 1) {
            float ov = __shfl_xor(bv, o); int oi = __shfl_xor(bi, o);
            if (ov > bv || (ov == bv && oi < bi)) { bv = ov; bi = oi; }
        }
        int owner = bi & 63, slot = bi >> 6;
        if (lane == owner) {
#pragma unroll
            for (int i = 0; i < 16; ++i) if (slot == i) v[i] = -INFINITY;
        }
        if (lane == k) {
            mix_out[(long)row * KTOP + k] = bv;
            clus_out[(long)row * KTOP + k] = (float)(bi >> 5);
        }
    }
}

// ---------------- K9: column softmax stats ----------------
__global__ __launch_bounds__(256) void col_stats_part(const float* __restrict__ logits,
                                                      float* __restrict__ pmax, float* __restrict__ psum) {
    int b = blockIdx.z, ms = blockIdx.y, npc = blockIdx.x;
    int np = npc * 256 + threadIdx.x;
    const float* p = logits + ((long)b * MTOK + ms * 128) * NP + np;
    float mx = -INFINITY, s = 0.f;
    for (int m = 0; m < 128; ++m) {
        float v = p[(long)m * NP];
        float nm = fmaxf(mx, v);
        s = s * __expf(mx - nm) + __expf(v - nm);
        mx = nm;
    }
    long o = ((long)b * 8 + ms) * NP + np;
    pmax[o] = mx; psum[o] = s;
}

__global__ __launch_bounds__(256) void col_stats_merge(const float* __restrict__ pmax, const float* __restrict__ psum,
                                                       float* __restrict__ cmax, float* __restrict__ csumInv) {
    int b = blockIdx.y;
    int np = blockIdx.x * 256 + threadIdx.x;
    float mx = -INFINITY;
#pragma unroll
    for (int ms = 0; ms < 8; ++ms) mx = fmaxf(mx, pmax[((long)b * 8 + ms) * NP + np]);
    float s = 0.f;
#pragma unroll
    for (int ms = 0; ms < 8; ++ms) {
        long o = ((long)b * 8 + ms) * NP + np;
        s += psum[o] * __expf(pmax[o] - mx);
    }
    cmax[(long)b * NP + np] = mx;
    csumInv[(long)b * NP + np] = 1.0f / s;
}

// ---------------- K10: dispT bf16 = softmax-over-m(logits)^T, tiled transpose ----------------
__global__ __launch_bounds__(256) void make_dispT(const float* __restrict__ logits,
                                                  const float* __restrict__ cmax, const float* __restrict__ cinv,
                                                  ushort* __restrict__ dispT) {
    __shared__ float tile[64][65];
    int b = blockIdx.z, np0 = blockIdx.x * 64, m0 = blockIdx.y * 64;
    int tr = threadIdx.x >> 6, tc = threadIdx.x & 63;
    const float* src = logits + ((long)b * MTOK + m0) * NP + np0;
#pragma unroll
    for (int i = 0; i < 16; ++i) {
        int m = tr * 16 + i;
        tile[m][tc] = src[(long)m * NP + tc];
    }
    __syncthreads();
#pragma unroll
    for (int i = 0; i < 16; ++i) {
        int npl = tr * 16 + i;
        int np = np0 + npl;
        float mx = cmax[(long)b * NP + np], iv = cinv[(long)b * NP + np];
        float v = __expf(tile[tc][npl] - mx) * iv;
        dispT[((long)b * NP + np) * MTOK + (m0 + tc)] = bf16_rne(v);
    }
}

// ---------------- K11: comb bf16 = softmax-over-np(logits), elementwise ----------------
__global__ __launch_bounds__(256) void make_comb(const float* __restrict__ logits,
                                                 const float* __restrict__ rmax, const float* __restrict__ rinv,
                                                 ushort* __restrict__ comb) {
    long base = ((long)blockIdx.x * 256 + threadIdx.x) * 4;
    int row = (int)(base >> 10);
    float mx = rmax[row], iv = rinv[row];
    float4 v = *reinterpret_cast<const float4*>(logits + base);
    *reinterpret_cast<short4v*>(comb + base) = short4v{
        (short)bf16_rne(__expf(v.x - mx) * iv), (short)bf16_rne(__expf(v.y - mx) * iv),
        (short)bf16_rne(__expf(v.z - mx) * iv), (short)bf16_rne(__expf(v.w - mx) * iv)};
}

// ---------------- launch ----------------
extern "C" void kernel_launch(void* const* d_in, const int* in_sizes, int n_in,
                              void* d_out, int out_size, void* d_ws, size_t ws_size,
                              hipStream_t stream) {
    const float* x    = (const float*)d_in[0];
    const int*   ca   = (const int*)d_in[1];
    const float* phi  = (const float*)d_in[2];
    const float* scale= (const float*)d_in[3];
    const float* w1   = (const float*)d_in[4];
    const float* b1   = (const float*)d_in[5];
    const float* w2   = (const float*)d_in[6];
    const float* b2   = (const float*)d_in[7];
    float* out = (float*)d_out;
    float* ws  = (float*)d_ws;

    float*  xn       = ws;                                   // 6291456 f32
    float*  logits   = xn + 6291456;                         // 8388608 f32
    ushort* xnp_hi   = (ushort*)(logits + 8388608);          // 6291456 sh
    ushort* xnp_lo   = xnp_hi + 6291456;                     // 6291456 sh
    ushort* phT_hi   = xnp_lo + 6291456;                     // 786432 sh
    ushort* phT_lo   = phT_hi + 786432;                      // 786432 sh
    ushort* dispT_bf = phT_lo + 786432;                      // 8388608 sh
    ushort* comb_bf  = dispT_bf + 8388608;                   // 8388608 sh
    ushort* xs_bf    = comb_bf + 8388608;                    // 6291456 sh
    ushort* h_bf     = xs_bf + 6291456;                      // 16777216 sh
    float*  stats    = (float*)(h_bf + 16777216);
    float* rowmax    = stats;                 // 8192
    float* rowsumInv = rowmax + 8192;
    float* colmax    = rowsumInv + 8192;
    float* colsumInv = colmax + 8192;
    float* pmax      = colsumInv + 8192;      // 65536
    float* psum      = pmax + 65536;          // 65536
    float* csum      = psum + 65536;          // 24576
    float* cmad      = csum + 24576;          // 24576
    float* Wbuf      = cmad + 24576;          // 24576
    float* ccnt      = Wbuf + 24576;          // 64
    float* spart     = ccnt + 64;             // 393216
    float* mpart     = spart + 393216;        // 393216
    float* cntpart   = mpart + 393216;        // 512
    float* ys        = xn;                    // alias: xn dead after xs GEMM

    float* out_y    = out;
    float* out_mix  = out + 6291456;
    float* out_clus = out + 6291456 + 65536;

    norm_x<<<BMT, 256, 0, stream>>>(x, xn);
    norm_phi_T<<<NP, 256, 0, stream>>>(phi, scale, phT_hi, phT_lo);

    cluster_sum<<<dim3(3, 16), 256, 0, stream>>>(xn, ca, spart, cntpart);
    reduce_parts<<<96, 256, 0, stream>>>(spart, csum, cntpart, ccnt, 1);
    cluster_mad<<<dim3(3, 16), 256, 0, stream>>>(xn, ca, csum, ccnt, mpart);
    reduce_parts<<<96, 256, 0, stream>>>(mpart, cmad, nullptr, nullptr, 0);
    compute_W<<<1, 1024, 0, stream>>>(cmad, ccnt, Wbuf);
    apply_W<<<BMT, 192, 0, stream>>>(xn, ca, Wbuf);
    split_xn<<<6144, 256, 0, stream>>>(xn, xnp_hi, xnp_lo);

    // logits = xn . phin  (split-pair 3-MFMA, f32-accurate; A,B via global_load_lds)
    gemm2<true, 0, 0, false, 0><<<dim3(8, 64, 1), 256, 0, stream>>>(
        xnp_hi, xnp_lo, nullptr, phT_hi, phT_lo, logits, nullptr,
        DD, DD, DD, NP, 0, 0, 0, nullptr, 0);

    row_topk<<<BMT, 64, 0, stream>>>(logits, out_mix, out_clus, rowmax, rowsumInv);
    col_stats_part<<<dim3(4, 8, NB), 256, 0, stream>>>(logits, pmax, psum);
    col_stats_merge<<<dim3(4, NB), 256, 0, stream>>>(pmax, psum, colmax, colsumInv);
    make_dispT<<<dim3(16, 16, NB), 256, 0, stream>>>(logits, colmax, colsumInv, dispT_bf);
    make_comb<<<8192, 256, 0, stream>>>(logits, rowmax, rowsumInv, comb_bf);

    // xs[b] = dispT . xn[b]  -> bf16  (A=dispT_bf gload_lds, B=xn f32 reg-staged)
    gemm2<false, 0, 0, true, 0><<<dim3(6, 8, NB), 256, 0, stream>>>(
        dispT_bf, nullptr, xn, nullptr, nullptr, nullptr, xs_bf,
        MTOK, MTOK, DD, DD,
        (long)NP * MTOK, (long)MTOK * DD, (long)NP * DD, nullptr, 0);

    // h[n] = gelu(xs_rows(n) . w1[n] + b1[n]) -> bf16  (A tokens via remap)
    gemm2<false, 1, 2, true, 0><<<dim3(16, 2, NEXP), 256, 0, stream>>>(
        xs_bf, nullptr, w1, nullptr, nullptr, nullptr, h_bf,
        DD, DD, HH, HH,
        0, (long)DD * HH, (long)256 * HH, b1, HH);

    // ys = h_rows(n) . w2[n] + b2[n] -> f32 [b][np][768] (token-remapped C)
    gemm2<false, 0, 1, false, 1><<<dim3(6, 2, NEXP), 256, 0, stream>>>(
        h_bf, nullptr, w2, nullptr, nullptr, ys, nullptr,
        HH, HH, DD, DD,
        (long)256 * HH, (long)HH * DD, 0, b2, DD);

    // y[b] = comb . ys[b] -> f32 out
    gemm2<false, 0, 0, false, 0><<<dim3(6, 8, NB), 256, 0, stream>>>(
        comb_bf, nullptr, ys, nullptr, nullptr, out_y, nullptr,
        NP, NP, DD, DD,
        (long)MTOK * NP, (long)NP * DD, (long)MTOK * DD, nullptr, 0);
}

// Round 6
// 591.383 us; speedup vs baseline: 2.9838x; 1.2876x over previous
//
#include <hip/hip_runtime.h>
#include <cmath>

// ---------------- problem constants ----------------
// B=8, M=1024, D=768, N=32, P=32, K=8, H=2048
#define NB    8
#define MTOK  1024
#define BMT   8192      // B*M
#define DD    768
#define NEXP  32
#define PSLOT 32
#define NP    1024      // N*P
#define KTOP  8
#define HH    2048

#define SLICES 128      // partial-sum slices for cluster stats
#define TPS    64       // tokens per slice (SLICES*TPS == BMT)

typedef unsigned short ushort;
typedef __attribute__((ext_vector_type(8))) short short8v;   // 8 bf16 = 4 VGPR
typedef __attribute__((ext_vector_type(4))) short short4v;   // 8 bytes
typedef __attribute__((ext_vector_type(4))) float f32x4;

__device__ __forceinline__ ushort bf16_rne(float x) {
    unsigned u = __float_as_uint(x);
    unsigned r = (u + 0x7FFFu + ((u >> 16) & 1u)) >> 16;
    return (ushort)r;
}
__device__ __forceinline__ float bf16_to_f(ushort h) {
    return __uint_as_float(((unsigned)h) << 16);
}
__device__ __forceinline__ void split2(float x, ushort& hi, ushort& lo) {
    hi = bf16_rne(x);
    lo = bf16_rne(x - bf16_to_f(hi));
}

// async global->LDS, 16B per lane; lds dest is wave-uniform base + lane*16
__device__ __forceinline__ void gl_lds16(const ushort* g, ushort* l) {
    __builtin_amdgcn_global_load_lds(
        (const __attribute__((address_space(1))) void*)g,
        (__attribute__((address_space(3))) void*)l, 16, 0, 0);
}

// ---------------- K1: token L2 normalize ----------------
__global__ __launch_bounds__(256) void norm_x(const float* __restrict__ x, float* __restrict__ xn) {
    int tok = blockIdx.x;
    int t = threadIdx.x;
    const float* p = x + (long)tok * DD;
    float v0 = p[t], v1 = p[t + 256], v2 = p[t + 512];
    float ss = v0 * v0 + v1 * v1 + v2 * v2;
#pragma unroll
    for (int o = 32; o; o >>= 1) ss += __shfl_xor(ss, o);
    __shared__ float sred[4];
    if ((t & 63) == 0) sred[t >> 6] = ss;
    __syncthreads();
    ss = sred[0] + sred[1] + sred[2] + sred[3];
    float inv = 1.0f / fmaxf(sqrtf(ss), 1e-12f);
    float* q = xn + (long)tok * DD;
    q[t] = v0 * inv; q[t + 256] = v1 * inv; q[t + 512] = v2 * inv;
}

// ---------------- K2: phi normalize -> transposed split pair [np][d] ----------------
__global__ __launch_bounds__(256) void norm_phi_T(const float* __restrict__ phi, const float* __restrict__ scale,
                                                  ushort* __restrict__ phT_hi, ushort* __restrict__ phT_lo) {
    int np = blockIdx.x;           // 1024 blocks
    int t = threadIdx.x;
    float ss = 0.f;
    for (int d = t; d < DD; d += 256) {
        float v = phi[(long)d * NP + np];
        ss += v * v;
    }
#pragma unroll
    for (int o = 32; o; o >>= 1) ss += __shfl_xor(ss, o);
    __shared__ float sred[4];
    if ((t & 63) == 0) sred[t >> 6] = ss;
    __syncthreads();
    ss = sred[0] + sred[1] + sred[2] + sred[3];
    float sc = scale[0] / fmaxf(sqrtf(ss), 1e-12f);
    for (int d = t; d < DD; d += 256) {
        float v = phi[(long)d * NP + np] * sc;
        ushort h, l; split2(v, h, l);
        phT_hi[(long)np * DD + d] = h;
        phT_lo[(long)np * DD + d] = l;
    }
}

// ---------------- K3: per-cluster sums (deterministic partials, 128 slices) ----------------
__global__ __launch_bounds__(256) void cluster_sum(const float* __restrict__ xn, const int* __restrict__ ca,
                                                   float* __restrict__ spart, float* __restrict__ cntpart) {
    __shared__ float s[NEXP][256];
    __shared__ float cnt[NEXP];
    int chunk = blockIdx.x, slice = blockIdx.y, t = threadIdx.x;
#pragma unroll
    for (int n = 0; n < NEXP; ++n) s[n][t] = 0.f;
    if (t < NEXP) cnt[t] = 0.f;
    __syncthreads();
    int tok0 = slice * TPS;
    for (int i = 0; i < TPS; ++i) {
        int tok = tok0 + i;
        int a = ca[tok * KTOP];
        float v = xn[(long)tok * DD + chunk * 256 + t];
        s[a][t] += v;
        if (chunk == 0 && t == 0) cnt[a] += 1.f;
    }
    __syncthreads();
    for (int n = 0; n < NEXP; ++n)
        spart[(long)slice * (NEXP * DD) + n * DD + chunk * 256 + t] = s[n][t];
    if (chunk == 0 && t < NEXP) cntpart[slice * NEXP + t] = cnt[t];
}

__global__ __launch_bounds__(256) void reduce_parts(const float* __restrict__ part, float* __restrict__ outv,
                                                    const float* __restrict__ cntpart, float* __restrict__ ccnt,
                                                    int doCnt) {
    int i = blockIdx.x * 256 + threadIdx.x;
    float s = 0.f;
#pragma unroll 8
    for (int sl = 0; sl < SLICES; ++sl) s += part[(long)sl * (NEXP * DD) + i];
    outv[i] = s;
    if (doCnt && i < NEXP) {
        float c = 0.f;
#pragma unroll 8
        for (int sl = 0; sl < SLICES; ++sl) c += cntpart[sl * NEXP + i];
        ccnt[i] = c;
    }
}

// ---------------- K4: per-cluster MAD partials ----------------
__global__ __launch_bounds__(256) void cluster_mad(const float* __restrict__ xn, const int* __restrict__ ca,
                                                   const float* __restrict__ csum, const float* __restrict__ ccnt,
                                                   float* __restrict__ mpart) {
    __shared__ float md[NEXP][256];
    __shared__ float mean[NEXP][256];
    int chunk = blockIdx.x, slice = blockIdx.y, t = threadIdx.x;
#pragma unroll
    for (int n = 0; n < NEXP; ++n) {
        float c = ccnt[n];
        mean[n][t] = (c > 0.f) ? csum[n * DD + chunk * 256 + t] / c : 0.f;
        md[n][t] = 0.f;
    }
    __syncthreads();
    int tok0 = slice * TPS;
    for (int i = 0; i < TPS; ++i) {
        int tok = tok0 + i;
        int a = ca[tok * KTOP];
        float v = xn[(long)tok * DD + chunk * 256 + t];
        md[a][t] += fabsf(v - mean[a][t]);
    }
    __syncthreads();
    for (int n = 0; n < NEXP; ++n)
        mpart[(long)slice * (NEXP * DD) + n * DD + chunk * 256 + t] = md[n][t];
}

// ---------------- K5: W = normalize(clamp(1/(mad+0.35))) ----------------
__global__ __launch_bounds__(1024) void compute_W(const float* __restrict__ cmad, const float* __restrict__ ccnt,
                                                  float* __restrict__ W) {
    __shared__ float s[16];
    int t = threadIdx.x;
    auto block_sum = [&](float v) -> float {
#pragma unroll
        for (int o = 32; o; o >>= 1) v += __shfl_xor(v, o);
        if ((t & 63) == 0) s[t >> 6] = v;
        __syncthreads();
        float tot = 0.f;
#pragma unroll
        for (int i = 0; i < 16; ++i) tot += s[i];
        __syncthreads();
        return tot;
    };
    const int TOT = NEXP * DD;
    float p = 0.f;
    for (int i = t; i < TOT; i += 1024) {
        int n = i / DD;
        float c = ccnt[n];
        float wm = (c > 0.f) ? cmad[i] / c : 0.f;
        p += 1.f / (wm + 0.35f);
    }
    float mean1 = block_sum(p) / (float)TOT;
    float clamp = 5.f * mean1;
    p = 0.f;
    for (int i = t; i < TOT; i += 1024) {
        int n = i / DD;
        float c = ccnt[n];
        float wm = (c > 0.f) ? cmad[i] / c : 0.f;
        p += fminf(1.f / (wm + 0.35f), clamp);
    }
    float mean2 = block_sum(p) / (float)TOT;
    float inv2 = 1.f / mean2;
    for (int i = t; i < TOT; i += 1024) {
        int n = i / DD;
        float c = ccnt[n];
        float wm = (c > 0.f) ? cmad[i] / c : 0.f;
        W[i] = fminf(1.f / (wm + 0.35f), clamp) * inv2;
    }
}

// ---------------- K6: xn *= W[assign]; also emit bf16 hi/lo pair ----------------
__global__ __launch_bounds__(192) void apply_W(float* __restrict__ xn, const int* __restrict__ ca,
                                               const float* __restrict__ W,
                                               ushort* __restrict__ hi, ushort* __restrict__ lo) {
    int tok = blockIdx.x;
    long d4 = (long)tok * DD + threadIdx.x * 4;
    int a = ca[tok * KTOP];
    float4 v = *reinterpret_cast<float4*>(xn + d4);
    float4 w = *reinterpret_cast<const float4*>(W + a * DD + threadIdx.x * 4);
    v.x *= w.x; v.y *= w.y; v.z *= w.z; v.w *= w.w;
    *reinterpret_cast<float4*>(xn + d4) = v;
    ushort h0,h1,h2,h3,l0,l1,l2,l3;
    split2(v.x,h0,l0); split2(v.y,h1,l1); split2(v.z,h2,l2); split2(v.w,h3,l3);
    *reinterpret_cast<short4v*>(hi + d4) = short4v{(short)h0,(short)h1,(short)h2,(short)h3};
    *reinterpret_cast<short4v*>(lo + d4) = short4v{(short)l0,(short)l1,(short)l2,(short)l3};
}

// ---------------- MFMA GEMM: BM=128, BN=128, BK=32, 256 thr, dbuf 2-phase ----------------
// A (bf16, pre-rounded) staged via global_load_lds with pre-swizzled source.
// PAIR (logits): A and B are hi/lo pairs, both gload_lds, 3-MFMA split accumulate.
// !PAIR: B from f32 [k][n] source, reg-prefetch (16 floats) + micro-transpose + swizzled ds_write.
// Swizzle: 16B slot s of row r stored at s ^ ((r>>1)&3)  -> 2-way reads (free).
// AMAP: 0 linear z-strided, 1 token remap (row -> (r>>5)*1024 + z*32 + (r&31)).
// EPI: 0 none, 1 +bias, 2 +bias+gelu.  CBF16: round C to bf16.  CMAP: 0 lin, 1 token remap.
template <bool PAIR, int AMAP, int EPI, bool CBF16, int CMAP>
__global__ __launch_bounds__(256) void gemm2(
    const ushort* __restrict__ Ah_g, const ushort* __restrict__ Al_g,
    const float*  __restrict__ Bf_g,
    const ushort* __restrict__ Bh_g, const ushort* __restrict__ Bl_g,
    float* __restrict__ Cf, ushort* __restrict__ Cb,
    int K, int lda, int ldb, int ldc,
    long sA, long sB, long sC,
    const float* __restrict__ bias, int biasStride) {
    __shared__ __attribute__((aligned(16))) ushort lds[PAIR ? 32768 : 16384];

    // XCD-aware bijective remap (all grids multiples of 8)
    int orig = blockIdx.x + gridDim.x * (blockIdx.y + gridDim.y * blockIdx.z);
    int nwg = gridDim.x * gridDim.y * gridDim.z;
    int wg = (orig & 7) * (nwg >> 3) + (orig >> 3);
    int bx = wg % gridDim.x;
    int rest = wg / gridDim.x;
    int by = rest % gridDim.y;
    int z  = rest / gridDim.y;
    const int m0 = by * 128;
    const int n0 = bx * 128;

    const int tid = threadIdx.x, lane = tid & 63, w = tid >> 6;
    const int wr = w >> 1, wc = w & 1;          // 2x2 waves of 64x64
    const int lr = lane & 15, kh = lane >> 4;

    // staging coords: chunk c = i*256+tid; r=c>>2 row, sp=c&3 phys 16B slot
    long arow[2]; long brow[2]; int kOff[2];
#pragma unroll
    for (int i = 0; i < 2; ++i) {
        int c = i * 256 + tid;
        int r = c >> 2, sp = c & 3;
        kOff[i] = (sp ^ ((r >> 1) & 3)) << 3;   // element offset of logical slot
        int rg = m0 + r;
        if constexpr (AMAP == 0) arow[i] = (long)z * sA + (long)rg * lda;
        else arow[i] = ((long)(rg >> 5) * 1024 + (long)z * 32 + (rg & 31)) * (long)lda;
        brow[i] = (long)(n0 + r) * ldb;         // PAIR B rows (z=0 there)
    }
    // !PAIR B-staging coords
    const int kq = tid & 7, nq = tid >> 3;      // kq: 4 k-rows, nq: 4 n-cols
    float4 rB[4];

    f32x4 acc[4][4];
#pragma unroll
    for (int i = 0; i < 4; ++i)
#pragma unroll
        for (int j = 0; j < 4; ++j) acc[i][j] = (f32x4)(0.f);

    auto stage = [&](int buf, int kk0) {
#pragma unroll
        for (int i = 0; i < 2; ++i) {
            int ldso = (PAIR ? buf * 16384 : buf * 8192) + (i * 256 + w * 64) * 8;
            gl_lds16(Ah_g + arow[i] + kk0 + kOff[i], &lds[ldso]);
            if constexpr (PAIR)
                gl_lds16(Al_g + arow[i] + kk0 + kOff[i], &lds[ldso + 4096]);
        }
        if constexpr (PAIR) {
#pragma unroll
            for (int i = 0; i < 2; ++i) {
                int ldso = buf * 16384 + 8192 + (i * 256 + w * 64) * 8;
                gl_lds16(Bh_g + brow[i] + kk0 + kOff[i], &lds[ldso]);
                gl_lds16(Bl_g + brow[i] + kk0 + kOff[i], &lds[ldso + 4096]);
            }
        } else {
#pragma unroll
            for (int dk = 0; dk < 4; ++dk)
                rB[dk] = *reinterpret_cast<const float4*>(
                    Bf_g + (long)z * sB + (long)(kk0 + kq * 4 + dk) * ldb + n0 + nq * 4);
        }
    };

    auto bwrite = [&](int buf) {
        if constexpr (!PAIR) {
            ushort hv[4][4];
#pragma unroll
            for (int dk = 0; dk < 4; ++dk) {
                hv[dk][0] = bf16_rne(rB[dk].x); hv[dk][1] = bf16_rne(rB[dk].y);
                hv[dk][2] = bf16_rne(rB[dk].z); hv[dk][3] = bf16_rne(rB[dk].w);
            }
#pragma unroll
            for (int dn = 0; dn < 4; ++dn) {
                int n = nq * 4 + dn;
                int phys = (kq >> 1) ^ ((n >> 1) & 3);
                int off = buf * 8192 + 4096 + n * 32 + phys * 8 + (kq & 1) * 4;
                *reinterpret_cast<short4v*>(&lds[off]) =
                    short4v{(short)hv[0][dn], (short)hv[1][dn], (short)hv[2][dn], (short)hv[3][dn]};
            }
        }
    };

    auto compute = [&](int buf) {
        const int aB = PAIR ? buf * 16384 : buf * 8192;
        const int bB = PAIR ? buf * 16384 + 8192 : buf * 8192 + 4096;
        short8v bh[4], bl[4];
#pragma unroll
        for (int nj = 0; nj < 4; ++nj) {
            int rb = wc * 64 + nj * 16 + lr;
            int off = bB + rb * 32 + ((kh ^ ((rb >> 1) & 3)) << 3);
            bh[nj] = *reinterpret_cast<const short8v*>(&lds[off]);
            if constexpr (PAIR) bl[nj] = *reinterpret_cast<const short8v*>(&lds[off + 4096]);
        }
#pragma unroll
        for (int mi = 0; mi < 4; ++mi) {
            int ra = wr * 64 + mi * 16 + lr;
            int off = aB + ra * 32 + ((kh ^ ((ra >> 1) & 3)) << 3);
            short8v ah = *reinterpret_cast<const short8v*>(&lds[off]);
            if constexpr (PAIR) {
                short8v al = *reinterpret_cast<const short8v*>(&lds[off + 4096]);
#pragma unroll
                for (int nj = 0; nj < 4; ++nj) {
                    acc[mi][nj] = __builtin_amdgcn_mfma_f32_16x16x32_bf16(ah, bh[nj], acc[mi][nj], 0, 0, 0);
                    acc[mi][nj] = __builtin_amdgcn_mfma_f32_16x16x32_bf16(ah, bl[nj], acc[mi][nj], 0, 0, 0);
                    acc[mi][nj] = __builtin_amdgcn_mfma_f32_16x16x32_bf16(al, bh[nj], acc[mi][nj], 0, 0, 0);
                }
            } else {
#pragma unroll
                for (int nj = 0; nj < 4; ++nj)
                    acc[mi][nj] = __builtin_amdgcn_mfma_f32_16x16x32_bf16(ah, bh[nj], acc[mi][nj], 0, 0, 0);
            }
        }
    };

    // ---- 2-phase double-buffered K-loop
    const int nt = K >> 5;
    stage(0, 0);
    __syncthreads();                 // drains vmcnt -> A(0) in LDS, rB(0) in regs
    if constexpr (!PAIR) { bwrite(0); __syncthreads(); }
    for (int t = 0; t < nt; ++t) {
        int cur = t & 1;
        if (t + 1 < nt) stage(1 - cur, (t + 1) << 5);
        compute(cur);
        __syncthreads();             // drains vmcnt: next-tile A landed during compute
        if constexpr (!PAIR) {
            if (t + 1 < nt) { bwrite(1 - cur); __syncthreads(); }
        }
    }

    // ---- epilogue
#pragma unroll
    for (int mi = 0; mi < 4; ++mi)
#pragma unroll
        for (int j = 0; j < 4; ++j) {
            int rg = m0 + wr * 64 + mi * 16 + kh * 4 + j;
            long roff;
            if constexpr (CMAP == 1) roff = ((long)(rg >> 5) * 1024 + (long)z * 32 + (rg & 31)) * (long)ldc;
            else                     roff = (long)z * sC + (long)rg * ldc;
#pragma unroll
            for (int nj = 0; nj < 4; ++nj) {
                int col = n0 + wc * 64 + nj * 16 + lr;
                float v = acc[mi][nj][j];
                if constexpr (EPI >= 1) v += bias[(long)z * biasStride + col];
                if constexpr (EPI == 2) v = 0.5f * v * (1.0f + erff(v * 0.70710678118654752f));
                if constexpr (CBF16) Cb[roff + col] = bf16_rne(v);
                else                 Cf[roff + col] = v;
            }
        }
}

// ---------------- K8: per-row top-8 + row softmax stats ----------------
__global__ __launch_bounds__(64) void row_topk(const float* __restrict__ logits,
                                               float* __restrict__ mix_out, float* __restrict__ clus_out,
                                               float* __restrict__ rowmax, float* __restrict__ rowsumInv) {
    int row = blockIdx.x;
    int lane = threadIdx.x;
    const float* p = logits + (long)row * NP;
    float v[16];
#pragma unroll
    for (int i = 0; i < 16; ++i) v[i] = p[lane + i * 64];
    float mx = v[0];
#pragma unroll
    for (int i = 1; i < 16; ++i) mx = fmaxf(mx, v[i]);
#pragma unroll
    for (int o = 32; o; o >>= 1) mx = fmaxf(mx, __shfl_xor(mx, o));
    float s = 0.f;
#pragma unroll
    for (int i = 0; i < 16; ++i) s += __expf(v[i] - mx);
#pragma unroll
    for (int o = 32; o; o >>= 1) s += __shfl_xor(s, o);
    if (lane == 0) { rowmax[row] = mx; rowsumInv[row] = 1.0f / s; }
#pragma unroll
    for (int k = 0; k < KTOP; ++k) {
        float bv = -INFINITY; int bi = 1 << 30;
#pragma unroll
        for (int i = 0; i < 16; ++i) {
            if (v[i] > bv) { bv = v[i]; bi = lane + i * 64; }
        }
#pragma unroll
        for (int o = 32; o; o >>= 1) {
            float ov = __shfl_xor(bv, o); int oi = __shfl_xor(bi, o);
            if (ov > bv || (ov == bv && oi < bi)) { bv = ov; bi = oi; }
        }
        int owner = bi & 63, slot = bi >> 6;
        if (lane == owner) {
#pragma unroll
            for (int i = 0; i < 16; ++i) if (slot == i) v[i] = -INFINITY;
        }
        if (lane == k) {
            mix_out[(long)row * KTOP + k] = bv;
            clus_out[(long)row * KTOP + k] = (float)(bi >> 5);
        }
    }
}

// ---------------- K9: column softmax stats ----------------
__global__ __launch_bounds__(256) void col_stats_part(const float* __restrict__ logits,
                                                      float* __restrict__ pmax, float* __restrict__ psum) {
    int b = blockIdx.z, ms = blockIdx.y, npc = blockIdx.x;
    int np = npc * 256 + threadIdx.x;
    const float* p = logits + ((long)b * MTOK + ms * 128) * NP + np;
    float mx = -INFINITY, s = 0.f;
    for (int m = 0; m < 128; ++m) {
        float v = p[(long)m * NP];
        float nm = fmaxf(mx, v);
        s = s * __expf(mx - nm) + __expf(v - nm);
        mx = nm;
    }
    long o = ((long)b * 8 + ms) * NP + np;
    pmax[o] = mx; psum[o] = s;
}

__global__ __launch_bounds__(256) void col_stats_merge(const float* __restrict__ pmax, const float* __restrict__ psum,
                                                       float* __restrict__ cmax, float* __restrict__ csumInv) {
    int b = blockIdx.y;
    int np = blockIdx.x * 256 + threadIdx.x;
    float mx = -INFINITY;
#pragma unroll
    for (int ms = 0; ms < 8; ++ms) mx = fmaxf(mx, pmax[((long)b * 8 + ms) * NP + np]);
    float s = 0.f;
#pragma unroll
    for (int ms = 0; ms < 8; ++ms) {
        long o = ((long)b * 8 + ms) * NP + np;
        s += psum[o] * __expf(pmax[o] - mx);
    }
    cmax[(long)b * NP + np] = mx;
    csumInv[(long)b * NP + np] = 1.0f / s;
}

// ---------------- K10: dispT bf16 = softmax-over-m(logits)^T, tiled transpose ----------------
__global__ __launch_bounds__(256) void make_dispT(const float* __restrict__ logits,
                                                  const float* __restrict__ cmax, const float* __restrict__ cinv,
                                                  ushort* __restrict__ dispT) {
    __shared__ float tile[64][65];
    int b = blockIdx.z, np0 = blockIdx.x * 64, m0 = blockIdx.y * 64;
    int tr = threadIdx.x >> 6, tc = threadIdx.x & 63;
    const float* src = logits + ((long)b * MTOK + m0) * NP + np0;
#pragma unroll
    for (int i = 0; i < 16; ++i) {
        int m = tr * 16 + i;
        tile[m][tc] = src[(long)m * NP + tc];
    }
    __syncthreads();
#pragma unroll
    for (int i = 0; i < 16; ++i) {
        int npl = tr * 16 + i;
        int np = np0 + npl;
        float mx = cmax[(long)b * NP + np], iv = cinv[(long)b * NP + np];
        float v = __expf(tile[tc][npl] - mx) * iv;
        dispT[((long)b * NP + np) * MTOK + (m0 + tc)] = bf16_rne(v);
    }
}

// ---------------- K11: comb bf16 = softmax-over-np(logits), elementwise ----------------
__global__ __launch_bounds__(256) void make_comb(const float* __restrict__ logits,
                                                 const float* __restrict__ rmax, const float* __restrict__ rinv,
                                                 ushort* __restrict__ comb) {
    long base = ((long)blockIdx.x * 256 + threadIdx.x) * 4;
    int row = (int)(base >> 10);
    float mx = rmax[row], iv = rinv[row];
    float4 v = *reinterpret_cast<const float4*>(logits + base);
    *reinterpret_cast<short4v*>(comb + base) = short4v{
        (short)bf16_rne(__expf(v.x - mx) * iv), (short)bf16_rne(__expf(v.y - mx) * iv),
        (short)bf16_rne(__expf(v.z - mx) * iv), (short)bf16_rne(__expf(v.w - mx) * iv)};
}

// ---------------- launch ----------------
extern "C" void kernel_launch(void* const* d_in, const int* in_sizes, int n_in,
                              void* d_out, int out_size, void* d_ws, size_t ws_size,
                              hipStream_t stream) {
    const float* x    = (const float*)d_in[0];
    const int*   ca   = (const int*)d_in[1];
    const float* phi  = (const float*)d_in[2];
    const float* scale= (const float*)d_in[3];
    const float* w1   = (const float*)d_in[4];
    const float* b1   = (const float*)d_in[5];
    const float* w2   = (const float*)d_in[6];
    const float* b2   = (const float*)d_in[7];
    float* out = (float*)d_out;
    float* ws  = (float*)d_ws;

    float*  xn       = ws;                                   // 6291456 f32
    float*  logits   = xn + 6291456;                         // 8388608 f32
    ushort* xnp_hi   = (ushort*)(logits + 8388608);          // 6291456 sh
    ushort* xnp_lo   = xnp_hi + 6291456;                     // 6291456 sh
    ushort* phT_hi   = xnp_lo + 6291456;                     // 786432 sh
    ushort* phT_lo   = phT_hi + 786432;                      // 786432 sh
    ushort* dispT_bf = phT_lo + 786432;                      // 8388608 sh
    ushort* comb_bf  = dispT_bf + 8388608;                   // 8388608 sh
    ushort* xs_bf    = comb_bf + 8388608;                    // 6291456 sh
    ushort* h_bf     = xs_bf + 6291456;                      // 16777216 sh
    float*  stats    = (float*)(h_bf + 16777216);
    float* rowmax    = stats;                 // 8192
    float* rowsumInv = rowmax + 8192;
    float* colmax    = rowsumInv + 8192;
    float* colsumInv = colmax + 8192;
    float* pmax      = colsumInv + 8192;      // 65536
    float* psum      = pmax + 65536;          // 65536
    float* csum      = psum + 65536;          // 24576
    float* cmad      = csum + 24576;          // 24576
    float* Wbuf      = cmad + 24576;          // 24576
    float* ccnt      = Wbuf + 24576;          // 64
    float* cntpart   = ccnt + 64;             // SLICES*NEXP = 4096
    float* spart     = cntpart + 4096;        // SLICES*NEXP*DD = 3145728
    float* mpart     = spart + 3145728;       // 3145728
    float* ys        = xn;                    // alias: xn dead after xs GEMM

    float* out_y    = out;
    float* out_mix  = out + 6291456;
    float* out_clus = out + 6291456 + 65536;

    norm_x<<<BMT, 256, 0, stream>>>(x, xn);
    norm_phi_T<<<NP, 256, 0, stream>>>(phi, scale, phT_hi, phT_lo);

    cluster_sum<<<dim3(3, SLICES), 256, 0, stream>>>(xn, ca, spart, cntpart);
    reduce_parts<<<96, 256, 0, stream>>>(spart, csum, cntpart, ccnt, 1);
    cluster_mad<<<dim3(3, SLICES), 256, 0, stream>>>(xn, ca, csum, ccnt, mpart);
    reduce_parts<<<96, 256, 0, stream>>>(mpart, cmad, nullptr, nullptr, 0);
    compute_W<<<1, 1024, 0, stream>>>(cmad, ccnt, Wbuf);
    apply_W<<<BMT, 192, 0, stream>>>(xn, ca, Wbuf, xnp_hi, xnp_lo);

    // logits = xn . phin  (split-pair 3-MFMA, f32-accurate; A,B via global_load_lds)
    gemm2<true, 0, 0, false, 0><<<dim3(8, 64, 1), 256, 0, stream>>>(
        xnp_hi, xnp_lo, nullptr, phT_hi, phT_lo, logits, nullptr,
        DD, DD, DD, NP, 0, 0, 0, nullptr, 0);

    row_topk<<<BMT, 64, 0, stream>>>(logits, out_mix, out_clus, rowmax, rowsumInv);
    col_stats_part<<<dim3(4, 8, NB), 256, 0, stream>>>(logits, pmax, psum);
    col_stats_merge<<<dim3(4, NB), 256, 0, stream>>>(pmax, psum, colmax, colsumInv);
    make_dispT<<<dim3(16, 16, NB), 256, 0, stream>>>(logits, colmax, colsumInv, dispT_bf);
    make_comb<<<8192, 256, 0, stream>>>(logits, rowmax, rowsumInv, comb_bf);

    // xs[b] = dispT . xn[b]  -> bf16  (A=dispT_bf gload_lds, B=xn f32 reg-staged)
    gemm2<false, 0, 0, true, 0><<<dim3(6, 8, NB), 256, 0, stream>>>(
        dispT_bf, nullptr, xn, nullptr, nullptr, nullptr, xs_bf,
        MTOK, MTOK, DD, DD,
        (long)NP * MTOK, (long)MTOK * DD, (long)NP * DD, nullptr, 0);

    // h[n] = gelu(xs_rows(n) . w1[n] + b1[n]) -> bf16  (A tokens via remap)
    gemm2<false, 1, 2, true, 0><<<dim3(16, 2, NEXP), 256, 0, stream>>>(
        xs_bf, nullptr, w1, nullptr, nullptr, nullptr, h_bf,
        DD, DD, HH, HH,
        0, (long)DD * HH, (long)256 * HH, b1, HH);

    // ys = h_rows(n) . w2[n] + b2[n] -> f32 [b][np][768] (token-remapped C)
    gemm2<false, 0, 1, false, 1><<<dim3(6, 2, NEXP), 256, 0, stream>>>(
        h_bf, nullptr, w2, nullptr, nullptr, ys, nullptr,
        HH, HH, DD, DD,
        (long)256 * HH, (long)HH * DD, 0, b2, DD);

    // y[b] = comb . ys[b] -> f32 out
    gemm2<false, 0, 0, false, 0><<<dim3(6, 8, NB), 256, 0, stream>>>(
        comb_bf, nullptr, ys, nullptr, nullptr, out_y, nullptr,
        NP, NP, DD, DD,
        (long)MTOK * NP, (long)NP * DD, (long)MTOK * DD, nullptr, 0);
}